// Round 1
// baseline (352.715 us; speedup 1.0000x reference)
//
#include <hip/hip_runtime.h>

#define H 360
#define W 720
#define NB 8

#define TX 48
#define TY 24
#define LTX (TX + 4)   // 52  Tc tile width  (halo 2)
#define LTY (TY + 4)   // 28  Tc tile height
#define NTX (TX + 2)   // 50  post-advection tile width (halo 1)
#define NTY (TY + 2)   // 26

#define R_EARTH 6371000.0f
#define DEG2RAD 0.017453292519943295f
#define DT_STEP 600.0f

__global__ __launch_bounds__(256) void ocean_step(
    const float* __restrict__ Tc,
    const float* __restrict__ ug,
    const float* __restrict__ vg,
    const float* __restrict__ lat,
    const float* __restrict__ lon,
    const float* __restrict__ mask,
    float* __restrict__ Tout)
{
    __shared__ float sT[LTY][LTX];   // Tc with halo 2 (W wrapped, H clamped)
    __shared__ float sN[NTY][NTX];   // post-advection Tn with halo 1 (0 outside domain)

    const int b  = blockIdx.z;
    const int by = blockIdx.y * TY;
    const int bx = blockIdx.x * TX;
    const int tid = threadIdx.x;

    const float dlat   = lat[1] - lat[0];            // -0.5
    const float dy     = R_EARTH * DEG2RAD * fabsf(dlat);
    const float sign_y = (dlat > 0.0f) ? 1.0f : -1.0f;
    const float inv_dy  = 1.0f / dy;
    const float inv_2dy = 0.5f / dy;
    const float dlon   = lon[1] - lon[0];            // 0.5

    const size_t plane = (size_t)H * W;
    const float* Tb = Tc + (size_t)b * plane;
    const float* ub = ug + (size_t)b * plane;
    const float* vb = vg + (size_t)b * plane;

    // ---- stage 1: load Tc tile (halo 2). W periodic, H clamped (clamped
    // rows are never consumed by in-domain points). ----
    for (int idx = tid; idx < LTY * LTX; idx += 256) {
        const int r = idx / LTX, c = idx % LTX;
        int gi = by - 2 + r;
        int gj = bx - 2 + c;
        gi = min(max(gi, 0), H - 1);
        gj = (gj + W) % W;
        sT[r][c] = Tb[gi * W + gj];
    }
    __syncthreads();

    // ---- stage 2: advection update on (TY+2)x(TX+2) region (halo 1 for the
    // filter). Out-of-domain positions are ZERO (filter is zero-padded in
    // BOTH H and W, even though dT_dx itself is periodic). ----
    for (int idx = tid; idx < NTY * NTX; idx += 256) {
        const int r = idx / NTX, c = idx % NTX;
        const int gi = by - 1 + r;
        const int gj = bx - 1 + c;
        float val = 0.0f;
        if (gi >= 0 && gi < H && gj >= 0 && gj < W) {
            const int lr = r + 1;   // gi - (by-2)
            const int lc = c + 1;   // gj - (bx-2)
            const float tc = sT[lr][lc];

            float dTdy;
            if (gi == 0)            dTdy = (sT[lr + 1][lc] - tc) * inv_dy;
            else if (gi == H - 1)   dTdy = (tc - sT[lr - 1][lc]) * inv_dy;
            else                    dTdy = (sT[lr + 1][lc] - sT[lr - 1][lc]) * inv_2dy;
            dTdy *= sign_y;

            const float latv = lat[gi];
            const float dx   = R_EARTH * DEG2RAD * dlon * cosf(latv * DEG2RAD);
            const float dTdx = (sT[lr][lc + 1] - sT[lr][lc - 1]) / (2.0f * dx);

            const int off = gi * W + gj;
            const float adv = ub[off] * dTdx + vb[off] * dTdy;
            val = tc - DT_STEP * adv * mask[off];
        }
        sN[r][c] = val;
    }
    __syncthreads();

    // ---- stage 3: 3x3 binomial filter (zero-padded via sN halo) * mask ----
    for (int idx = tid; idx < TY * TX; idx += 256) {
        const int r = idx / TX, c = idx % TX;
        const int gi = by + r, gj = bx + c;
        const int nr = r + 1, nc = c + 1;
        const float f =
            (sN[nr - 1][nc - 1] + sN[nr - 1][nc + 1] +
             sN[nr + 1][nc - 1] + sN[nr + 1][nc + 1]) * (1.0f / 16.0f) +
            (sN[nr - 1][nc] + sN[nr][nc - 1] +
             sN[nr][nc + 1] + sN[nr + 1][nc]) * (2.0f / 16.0f) +
            sN[nr][nc] * (4.0f / 16.0f);
        Tout[(size_t)b * plane + gi * W + gj] = f * mask[gi * W + gj];
    }
}

extern "C" void kernel_launch(void* const* d_in, const int* in_sizes, int n_in,
                              void* d_out, int out_size, void* d_ws, size_t ws_size,
                              hipStream_t stream)
{
    const float* T    = (const float*)d_in[0];
    const float* ug   = (const float*)d_in[1];
    const float* vg   = (const float*)d_in[2];
    const float* lat  = (const float*)d_in[3];
    const float* lon  = (const float*)d_in[4];
    const float* mask = (const float*)d_in[5];
    float* out = (float*)d_out;
    float* ws  = (float*)d_ws;   // one field: 8*360*720*4 = 8.3 MB

    dim3 grid(W / TX, H / TY, NB);   // 15 x 15 x 8 = 1800 blocks
    dim3 block(256);

    const float* src = T;
    for (int s = 0; s < 20; ++s) {
        // even steps -> ws, odd steps -> d_out; step 19 (odd) lands in d_out
        float* dst = ((s & 1) == 0) ? ws : out;
        ocean_step<<<grid, block, 0, stream>>>(src, ug, vg, lat, lon, mask, dst);
        src = dst;
    }
}